// Round 7
// baseline (209.571 us; speedup 1.0000x reference)
//
#include <hip/hip_runtime.h>
#include <math.h>

#define NQ      11253
#define MTOT    22506
#define MPAD    22528          // 176 * 128
#define LEN_IN  11253

typedef unsigned short u16;
typedef u16   u16x8 __attribute__((ext_vector_type(8)));
typedef float f32x4 __attribute__((ext_vector_type(4)));

__device__ __forceinline__ u16 f2bf(float x) {
    unsigned u = __float_as_uint(x);
    return (u16)((u + 0x7fffu + ((u >> 16) & 1u)) >> 16);   // RTN-even
}
__device__ __forceinline__ float bf2f(u16 h) {
    return __uint_as_float(((unsigned)h) << 16);
}
__device__ __forceinline__ void MFMA(f32x4& d, u16x8 a, u16x8 b) {
    asm("v_mfma_f32_16x16x32_bf16 %0, %1, %2, %0" : "+v"(d) : "v"(a), "v"(b));
}
// async global->LDS, 16B/lane. LDS dest = wave-uniform base + lane*16.
__device__ __forceinline__ void glds16(const void* g, void* l) {
    __builtin_amdgcn_global_load_lds(
        (const __attribute__((address_space(1))) unsigned int*)g,
        (__attribute__((address_space(3))) unsigned int*)l, 16, 0, 0);
}

// ---------------------------------------------------------------------------
// prep_w: weights -> bf16 [n][k] planes (transpose).
//   wvh = W_val; wolh = [W_off | W_att] (384 rows); wuh = W_out.
// ---------------------------------------------------------------------------
__global__ __launch_bounds__(256) void prep_w(
    const float* __restrict__ Wv, const float* __restrict__ Wo,
    const float* __restrict__ Wa, const float* __restrict__ Wu,
    u16* __restrict__ wvh, u16* __restrict__ wolh, u16* __restrict__ wuh)
{
    const int k = blockIdx.x;      // 0..255
    const int t = threadIdx.x;     // 0..255
    wvh[t * 256 + k] = f2bf(Wv[k * 256 + t]);
    wuh[t * 256 + k] = f2bf(Wu[k * 256 + t]);
    wolh[t * 256 + k] = f2bf(Wo[k * 256 + t]);
    if (t < 128) wolh[(256 + t) * 256 + k] = f2bf(Wa[k * 128 + t]);
}

// ---------------------------------------------------------------------------
// Fused stage-1 GEMM, grid (176, 5). BM=BN=128, BK=64, 4 waves (2x2),
// wave tile 64x64. A = fp32 (inputf for ny<2, query for ny>=2), reg-staged +
// converted to bf16, ds_write to XOR-swizzled slots (R6 ASRC1 path).
// B = bf16 [n][k] plane, pre-offset by ny, staged via global_load_lds w16
// with pre-swizzled source (R6 path).
// Epilogue: ny<2 -> valbf bf16 head-major [(b*8+g)*LEN_IN+pix][32] (R6 OUTMODE1);
//           ny>=2 -> offsets fp32 [m][256] / logits fp32 [m][128] (R6 OUTMODE2).
// ---------------------------------------------------------------------------
__global__ __launch_bounds__(256) void gemm_s1(
    const float* __restrict__ inputf, const float* __restrict__ query,
    const u16* __restrict__ wvh, const u16* __restrict__ wolh,
    const float* __restrict__ bias_v, const float* __restrict__ bias_o,
    const float* __restrict__ bias_a,
    float* __restrict__ offsets, float* __restrict__ logits,
    u16* __restrict__ valbf)
{
    __shared__ __align__(16) u16 AS0[128 * 64];
    __shared__ __align__(16) u16 BS0[128 * 64];

    const int tid = threadIdx.x;
    const int l = tid & 63, wid = tid >> 6;
    const int wr = wid >> 1, wc = wid & 1;
    const int lr = l & 15;
    const int bm = blockIdx.x * 128;
    const int ny = blockIdx.y;

    const float* A = (ny < 2) ? inputf : query;
    const u16*   B = (ny < 2) ? (wvh + ny * 128 * 256)
                              : (wolh + (ny - 2) * 128 * 256);

    f32x4 acc[4][4];
#pragma unroll
    for (int i = 0; i < 4; ++i)
#pragma unroll
        for (int j = 0; j < 4; ++j) acc[i][j] = (f32x4)0.f;

    for (int k0 = 0; k0 < 256; k0 += 64) {
        // ---- stage A: fp32 reg-stage -> bf16, swizzled ds_write (R6 ASRC1) ----
        {
            const int r = tid >> 1, h = tid & 1;
            const bool ok = (bm + r) < MTOT;
            const float* src = &A[(size_t)(bm + r) * 256 + k0 + h * 32];
            float4 f[8];
#pragma unroll
            for (int c = 0; c < 4; ++c) {
                f[2 * c]     = ok ? *(const float4*)(src + c * 8)     : make_float4(0.f,0.f,0.f,0.f);
                f[2 * c + 1] = ok ? *(const float4*)(src + c * 8 + 4) : make_float4(0.f,0.f,0.f,0.f);
            }
#pragma unroll
            for (int c = 0; c < 4; ++c) {
                const int s = h * 4 + c;
                const float* p = (const float*)&f[2 * c];
                u16x8 hv;
#pragma unroll
                for (int j = 0; j < 8; ++j) hv[j] = f2bf(p[j]);
                *(u16x8*)&AS0[r * 64 + ((s ^ (r & 7)) * 8)] = hv;
            }
        }
        // ---- stage B: global_load_lds w16, pre-swizzled source (R6) ----
#pragma unroll
        for (int j = 0; j < 4; ++j) {
            const int ld = wid * 4 + j;
            const int rn = ld * 8 + (l >> 3);
            const int gs = (l & 7) ^ (l >> 3);
            glds16(B + (size_t)rn * 256 + k0 + gs * 8, &BS0[ld * 512]);
        }
        __syncthreads();

        // ---- compute: 2 k-steps of 32 (R6) ----
#pragma unroll
        for (int kk = 0; kk < 2; ++kk) {
            const int ks = kk * 4 + (l >> 4);
            u16x8 a0[4], b0[4];
#pragma unroll
            for (int t4 = 0; t4 < 4; ++t4) {
                const int ra = wr * 64 + t4 * 16 + lr;
                const int rb = wc * 64 + t4 * 16 + lr;
                a0[t4] = *(const u16x8*)&AS0[ra * 64 + ((ks ^ (ra & 7)) * 8)];
                b0[t4] = *(const u16x8*)&BS0[rb * 64 + ((ks ^ (rb & 7)) * 8)];
            }
#pragma unroll
            for (int mt = 0; mt < 4; ++mt)
#pragma unroll
                for (int nt = 0; nt < 4; ++nt)
                    MFMA(acc[mt][nt], a0[mt], b0[nt]);
        }
        __syncthreads();
    }

    asm volatile("s_nop 7\n\ts_nop 7");   // MFMA -> VALU read hazard guard

    // epilogue: C/D map col=lane&15, row=(lane>>4)*4+reg
#pragma unroll
    for (int mt = 0; mt < 4; ++mt)
#pragma unroll
        for (int j = 0; j < 4; ++j) {
            const int m = bm + wr * 64 + mt * 16 + (l >> 4) * 4 + j;
            if (m >= MTOT) continue;
#pragma unroll
            for (int nt = 0; nt < 4; ++nt) {
                const int nl = wc * 64 + nt * 16 + lr;
                const float val = acc[mt][nt][j];
                if (ny < 2) {
                    const int n = ny * 128 + nl;
                    const int bi = (m >= LEN_IN) ? 1 : 0;
                    const int pix = m - bi * LEN_IN;
                    valbf[((size_t)((bi << 3) | (n >> 5)) * LEN_IN + pix) * 32 + (n & 31)]
                        = f2bf(val + bias_v[n]);
                } else {
                    const int n = (ny - 2) * 128 + nl;
                    if (n < 256) offsets[(size_t)m * 256 + n] = val + bias_o[n];
                    else logits[(size_t)m * 128 + (n - 256)] = val + bias_a[n - 256];
                }
            }
        }
}

// ---------------------------------------------------------------------------
// Out GEMM (byte-identical to R6 gemm2<256,1,0,0>): out = A@Wt^T + bias.
// A = bf16 inner, staged via global_load_lds w16 (src pre-swizzled).
// ---------------------------------------------------------------------------
__global__ __launch_bounds__(256) void gemm_out(
    const u16* __restrict__ Ah, const u16* __restrict__ Bh,
    const float* __restrict__ bias0, float* __restrict__ Cf)
{
    __shared__ __align__(16) u16 AS0[128 * 64];
    __shared__ __align__(16) u16 BS0[128 * 64];

    const int tid = threadIdx.x;
    const int l = tid & 63, wid = tid >> 6;
    const int wr = wid >> 1, wc = wid & 1;
    const int lr = l & 15;
    const int bm = blockIdx.x * 128, bn = blockIdx.y * 128;

    f32x4 acc[4][4];
#pragma unroll
    for (int i = 0; i < 4; ++i)
#pragma unroll
        for (int j = 0; j < 4; ++j) acc[i][j] = (f32x4)0.f;

    for (int k0 = 0; k0 < 256; k0 += 64) {
#pragma unroll
        for (int j = 0; j < 4; ++j) {
            const int ld = wid * 4 + j;
            const int r  = ld * 8 + (l >> 3);
            const int gs = (l & 7) ^ (l >> 3);
            glds16(Ah + (size_t)(bm + r) * 256 + k0 + gs * 8, &AS0[ld * 512]);
            glds16(Bh + (size_t)(bn + r) * 256 + k0 + gs * 8, &BS0[ld * 512]);
        }
        __syncthreads();

#pragma unroll
        for (int kk = 0; kk < 2; ++kk) {
            const int ks = kk * 4 + (l >> 4);
            u16x8 a0[4], b0[4];
#pragma unroll
            for (int t4 = 0; t4 < 4; ++t4) {
                const int ra = wr * 64 + t4 * 16 + lr;
                const int rb = wc * 64 + t4 * 16 + lr;
                a0[t4] = *(const u16x8*)&AS0[ra * 64 + ((ks ^ (ra & 7)) * 8)];
                b0[t4] = *(const u16x8*)&BS0[rb * 64 + ((ks ^ (rb & 7)) * 8)];
            }
#pragma unroll
            for (int mt = 0; mt < 4; ++mt)
#pragma unroll
                for (int nt = 0; nt < 4; ++nt)
                    MFMA(acc[mt][nt], a0[mt], b0[nt]);
        }
        __syncthreads();
    }

    asm volatile("s_nop 7\n\ts_nop 7");

#pragma unroll
    for (int mt = 0; mt < 4; ++mt)
#pragma unroll
        for (int j = 0; j < 4; ++j) {
            const int m = bm + wr * 64 + mt * 16 + (l >> 4) * 4 + j;
            if (m >= MTOT) continue;
#pragma unroll
            for (int nt = 0; nt < 4; ++nt) {
                const int n = bn + wc * 64 + nt * 16 + lr;
                Cf[(size_t)m * 256 + n] = acc[mt][nt][j] + bias0[n];
            }
        }
}

// ---------------------------------------------------------------------------
// Deformable sampling (byte-identical to R6): 8 queries/block, 32 lanes/query
// (8 heads x 4 lanes), lane owns 8 bf16 channels. 16 predicated gathers per
// level batched in registers, then unpack+FMA. Writes inner as single bf16.
// ---------------------------------------------------------------------------
__global__ __launch_bounds__(256) void deform_sample(
    const u16* __restrict__ valbf, const float* __restrict__ offsets,
    const float* __restrict__ logits, const float* __restrict__ refp,
    u16* __restrict__ inner)
{
    const int tid = threadIdx.x;
    const int qi = blockIdx.x * 8 + (tid >> 5);
    if (qi >= MTOT) return;
    const int lq = tid & 31;
    const int g = lq >> 2, d8 = (lq & 3) * 8;
    const int b = (qi >= NQ) ? 1 : 0;

    const float* lg  = logits  + (size_t)qi * 128 + g * 16;
    const float* off = offsets + (size_t)qi * 256 + g * 32;
    const float* ref = refp    + (size_t)qi * 8;
    const u16* vbase = valbf + ((size_t)(b * 8 + g) * LEN_IN) * 32 + d8;

    float w[16];
    float mx = -1e30f;
#pragma unroll
    for (int i = 0; i < 16; ++i) { w[i] = lg[i]; mx = fmaxf(mx, w[i]); }
    float s = 0.f;
#pragma unroll
    for (int i = 0; i < 16; ++i) { w[i] = __expf(w[i] - mx); s += w[i]; }
    const float inv = 1.f / s;

    constexpr int Hs[4] = {92, 46, 23, 12};
    constexpr int Ss[4] = {0, 8464, 10580, 11109};

    float acc[8];
#pragma unroll
    for (int j = 0; j < 8; ++j) acc[j] = 0.f;

#pragma unroll
    for (int l = 0; l < 4; ++l) {
        const int Hn = Hs[l];
        const float Hf = (float)Hn;
        const float rx = ref[l * 2 + 0];
        const float ry = ref[l * 2 + 1];
        const u16* vlev = vbase + (size_t)Ss[l] * 32;

        uint4 cv[16];
        float cw[16];
#pragma unroll
        for (int k = 0; k < 4; ++k) {
            const float ox = off[(l * 4 + k) * 2 + 0];
            const float oy = off[(l * 4 + k) * 2 + 1];
            const float x = (rx + ox / Hf) * Hf - 0.5f;
            const float y = (ry + oy / Hf) * Hf - 0.5f;
            float aw = w[l * 4 + k];
            if (!(y > -1.f && x > -1.f && y < Hf && x < Hf)) aw = 0.f;
            const float h0f = floorf(y), w0f = floorf(x);
            const float lh = y - h0f, lw = x - w0f;
            const float hh = 1.f - lh, hw = 1.f - lw;
            const int h0 = (int)h0f, w0 = (int)w0f;
            const int base = h0 * Hn + w0;
            const bool hv0 = (unsigned)h0 < (unsigned)Hn;
            const bool hv1 = (unsigned)(h0 + 1) < (unsigned)Hn;
            const bool wv0 = (unsigned)w0 < (unsigned)Hn;
            const bool wv1 = (unsigned)(w0 + 1) < (unsigned)Hn;
            const bool v00 = hv0 && wv0, v01 = hv0 && wv1;
            const bool v10 = hv1 && wv0, v11 = hv1 && wv1;
            cw[k * 4 + 0] = v00 ? hh * hw * aw : 0.f;
            cw[k * 4 + 1] = v01 ? hh * lw * aw : 0.f;
            cw[k * 4 + 2] = v10 ? lh * hw * aw : 0.f;
            cw[k * 4 + 3] = v11 ? lh * lw * aw : 0.f;
            cv[k * 4 + 0] = *(const uint4*)(vlev + (size_t)(v00 ? base : 0) * 32);
            cv[k * 4 + 1] = *(const uint4*)(vlev + (size_t)(v01 ? base + 1 : 0) * 32);
            cv[k * 4 + 2] = *(const uint4*)(vlev + (size_t)(v10 ? base + Hn : 0) * 32);
            cv[k * 4 + 3] = *(const uint4*)(vlev + (size_t)(v11 ? base + Hn + 1 : 0) * 32);
        }
#pragma unroll
        for (int i = 0; i < 16; ++i) {
            const float c_ = cw[i];
            const uint4 v = cv[i];
            acc[0] += __uint_as_float(v.x << 16) * c_;
            acc[1] += __uint_as_float(v.x & 0xffff0000u) * c_;
            acc[2] += __uint_as_float(v.y << 16) * c_;
            acc[3] += __uint_as_float(v.y & 0xffff0000u) * c_;
            acc[4] += __uint_as_float(v.z << 16) * c_;
            acc[5] += __uint_as_float(v.z & 0xffff0000u) * c_;
            acc[6] += __uint_as_float(v.w << 16) * c_;
            acc[7] += __uint_as_float(v.w & 0xffff0000u) * c_;
        }
    }

    u16x8 hv;
#pragma unroll
    for (int j = 0; j < 8; ++j) hv[j] = f2bf(acc[j] * inv);
    *(u16x8*)&inner[(size_t)qi * 256 + g * 32 + d8] = hv;
}

// ---------------------------------------------------------------------------
extern "C" void kernel_launch(void* const* d_in, const int* in_sizes, int n_in,
                              void* d_out, int out_size, void* d_ws, size_t ws_size,
                              hipStream_t stream)
{
    const float* query  = (const float*)d_in[0];
    const float* refp   = (const float*)d_in[1];
    const float* inputf = (const float*)d_in[2];
    const float* W_off  = (const float*)d_in[5];
    const float* b_off  = (const float*)d_in[6];
    const float* W_att  = (const float*)d_in[7];
    const float* b_att  = (const float*)d_in[8];
    const float* W_val  = (const float*)d_in[9];
    const float* b_val  = (const float*)d_in[10];
    const float* W_out  = (const float*)d_in[11];
    const float* b_out  = (const float*)d_in[12];
    float* out = (float*)d_out;

    char* ws = (char*)d_ws;
    size_t o = 0;
    float* offsets = (float*)(ws + o); o += (size_t)MTOT * 256 * 4;   // 23.05 MB
    float* logits  = (float*)(ws + o); o += (size_t)MTOT * 128 * 4;   // 11.52 MB
    u16*   valbf   = (u16*)  (ws + o); o += (size_t)MTOT * 256 * 2;   // 11.52 MB
    u16*   inner   = (u16*)  (ws + o); o += (size_t)MPAD * 256 * 2;   // 11.53 MB
    u16*   wvh     = (u16*)  (ws + o); o += 256 * 256 * 2;
    u16*   wolh    = (u16*)  (ws + o); o += 384 * 256 * 2;
    u16*   wuh     = (u16*)  (ws + o); o += 256 * 256 * 2;            // ~58.2 MB total

    dim3 blk(256);

    // weights -> bf16 planes
    hipLaunchKernelGGL(prep_w, dim3(256), blk, 0, stream,
                       W_val, W_off, W_att, W_out, wvh, wolh, wuh);

    // fused stage-1: value -> valbf (ny 0..1), [offsets|logits] (ny 2..4)
    hipLaunchKernelGGL(gemm_s1, dim3(176, 5), blk, 0, stream,
                       inputf, query, wvh, wolh, b_val, b_off, b_att,
                       offsets, logits, valbf);

    hipLaunchKernelGGL(deform_sample, dim3((MTOT + 7) / 8), blk, 0, stream,
                       valbf, offsets, logits, refp, inner);

    // out = inner @ W_out + b_out
    hipLaunchKernelGGL(gemm_out, dim3(176, 2), blk, 0, stream,
                       inner, wuh, b_out, out);
}

// Round 8
// 203.641 us; speedup vs baseline: 1.0291x; 1.0291x over previous
//
#include <hip/hip_runtime.h>
#include <math.h>

#define NQ      11253
#define MTOT    22506
#define MPAD    22528          // 176 * 128
#define LEN_IN  11253

typedef unsigned short u16;
typedef u16   u16x8 __attribute__((ext_vector_type(8)));
typedef float f32x4 __attribute__((ext_vector_type(4)));

__device__ __forceinline__ u16 f2bf(float x) {
    unsigned u = __float_as_uint(x);
    return (u16)((u + 0x7fffu + ((u >> 16) & 1u)) >> 16);   // RTN-even
}
__device__ __forceinline__ float bf2f(u16 h) {
    return __uint_as_float(((unsigned)h) << 16);
}
__device__ __forceinline__ void MFMA(f32x4& d, u16x8 a, u16x8 b) {
    asm("v_mfma_f32_16x16x32_bf16 %0, %1, %2, %0" : "+v"(d) : "v"(a), "v"(b));
}
// async global->LDS, 16B/lane. LDS dest = wave-uniform base + lane*16.
__device__ __forceinline__ void glds16(const void* g, void* l) {
    __builtin_amdgcn_global_load_lds(
        (const __attribute__((address_space(1))) unsigned int*)g,
        (__attribute__((address_space(3))) unsigned int*)l, 16, 0, 0);
}

// ---------------------------------------------------------------------------
// prep, grid (2816, 2):
//  y==0: inputf -> ih bf16, query -> qh bf16 (rows >= MTOT zeroed).
//  y==1 (x<256): weights -> bf16 [n][k] planes:
//     wvh = W_val; wolh = [W_off | W_att] (384 rows); wuh = W_out.
// ---------------------------------------------------------------------------
__global__ __launch_bounds__(256) void prep(
    const float* __restrict__ inputf, const float* __restrict__ query,
    const float* __restrict__ Wv, const float* __restrict__ Wo,
    const float* __restrict__ Wa, const float* __restrict__ Wu,
    u16* __restrict__ ih, u16* __restrict__ qh, u16* __restrict__ wvh,
    u16* __restrict__ wolh, u16* __restrict__ wuh)
{
    const int t = threadIdx.x;
    if (blockIdx.y == 0) {
        const int row = blockIdx.x * 8 + (t >> 5);
        const int col = (t & 31) * 8;
        const size_t idx = (size_t)row * 256 + col;
        const bool ok = row < MTOT;
        float4 a0 = make_float4(0.f,0.f,0.f,0.f), a1 = a0, b0 = a0, b1 = a0;
        if (ok) {
            a0 = *(const float4*)&inputf[idx]; a1 = *(const float4*)&inputf[idx + 4];
            b0 = *(const float4*)&query[idx];  b1 = *(const float4*)&query[idx + 4];
        }
        const float av[8] = {a0.x, a0.y, a0.z, a0.w, a1.x, a1.y, a1.z, a1.w};
        const float bv[8] = {b0.x, b0.y, b0.z, b0.w, b1.x, b1.y, b1.z, b1.w};
        u16x8 ha, hb;
#pragma unroll
        for (int j = 0; j < 8; ++j) { ha[j] = f2bf(av[j]); hb[j] = f2bf(bv[j]); }
        *(u16x8*)&ih[idx] = ha;
        *(u16x8*)&qh[idx] = hb;
    } else {
        const int k = blockIdx.x;
        if (k >= 256) return;
        wvh[t * 256 + k] = f2bf(Wv[k * 256 + t]);
        wuh[t * 256 + k] = f2bf(Wu[k * 256 + t]);
        wolh[t * 256 + k] = f2bf(Wo[k * 256 + t]);
        if (t < 128) wolh[(256 + t) * 256 + k] = f2bf(Wa[k * 128 + t]);
    }
}

// ---------------------------------------------------------------------------
// Fused stage-1 GEMM, grid (176, 5). BM=BN=128, BK=64, 4 waves (2x2), wave
// tile 64x64. Both A (ih/qh by ny) and B staged via global_load_lds w16 with
// pre-swizzled source; DOUBLE-BUFFERED LDS, one barrier per K-step:
//   stage(0); bar; for k: { if(k<3) stage(k+1, alt); compute(cur); bar; }
// Epilogue: ny<2 -> valbf bf16 head-major; ny>=2 -> offsets/logits fp32 (R7).
// ---------------------------------------------------------------------------
__global__ __launch_bounds__(256) void gemm_s1(
    const u16* __restrict__ ih, const u16* __restrict__ qh,
    const u16* __restrict__ wvh, const u16* __restrict__ wolh,
    const float* __restrict__ bias_v, const float* __restrict__ bias_o,
    const float* __restrict__ bias_a,
    float* __restrict__ offsets, float* __restrict__ logits,
    u16* __restrict__ valbf)
{
    __shared__ __align__(16) u16 AS[2][128 * 64];
    __shared__ __align__(16) u16 BS[2][128 * 64];

    const int tid = threadIdx.x;
    const int l = tid & 63, wid = tid >> 6;
    const int wr = wid >> 1, wc = wid & 1;
    const int lr = l & 15;
    const int bm = blockIdx.x * 128;
    const int ny = blockIdx.y;

    const u16* A = (ny < 2) ? ih : qh;
    const u16* B = (ny < 2) ? (wvh + ny * 128 * 256)
                            : (wolh + (ny - 2) * 128 * 256);

    f32x4 acc[4][4];
#pragma unroll
    for (int i = 0; i < 4; ++i)
#pragma unroll
        for (int j = 0; j < 4; ++j) acc[i][j] = (f32x4)0.f;

    const int rsub = l >> 3;
    const int gs = (l & 7) ^ rsub;               // source pre-swizzle

    // stage one BK=64 K-slab into buffer b
#define STAGE(b, k0)                                                          \
    {                                                                         \
        _Pragma("unroll")                                                     \
        for (int j = 0; j < 4; ++j) {                                         \
            const int ld = wid * 4 + j;                                       \
            const int r  = ld * 8 + rsub;                                     \
            glds16(A + (size_t)(bm + r) * 256 + (k0) + gs * 8, &AS[b][ld * 512]); \
            glds16(B + (size_t)r * 256 + (k0) + gs * 8, &BS[b][ld * 512]);    \
        }                                                                     \
    }

    STAGE(0, 0);
    __syncthreads();   // implicit vmcnt(0): buf0 ready

#pragma unroll
    for (int kt = 0; kt < 4; ++kt) {
        const int cur = kt & 1;
        if (kt < 3) STAGE(cur ^ 1, (kt + 1) * 64);   // prefetch overlaps MFMA
#pragma unroll
        for (int kk = 0; kk < 2; ++kk) {
            const int ks = kk * 4 + (l >> 4);
            u16x8 a0[4], b0[4];
#pragma unroll
            for (int t4 = 0; t4 < 4; ++t4) {
                const int ra = wr * 64 + t4 * 16 + lr;
                const int rb = wc * 64 + t4 * 16 + lr;
                a0[t4] = *(const u16x8*)&AS[cur][ra * 64 + ((ks ^ (ra & 7)) * 8)];
                b0[t4] = *(const u16x8*)&BS[cur][rb * 64 + ((ks ^ (rb & 7)) * 8)];
            }
#pragma unroll
            for (int mt = 0; mt < 4; ++mt)
#pragma unroll
                for (int nt = 0; nt < 4; ++nt)
                    MFMA(acc[mt][nt], a0[mt], b0[nt]);
        }
        __syncthreads();   // drains prefetch glds; releases buffers
    }
#undef STAGE

    asm volatile("s_nop 7\n\ts_nop 7");   // MFMA -> VALU read hazard guard

    // epilogue (R7): C/D map col=lane&15, row=(lane>>4)*4+reg
#pragma unroll
    for (int mt = 0; mt < 4; ++mt)
#pragma unroll
        for (int j = 0; j < 4; ++j) {
            const int m = bm + wr * 64 + mt * 16 + (l >> 4) * 4 + j;
            if (m >= MTOT) continue;
#pragma unroll
            for (int nt = 0; nt < 4; ++nt) {
                const int nl = wc * 64 + nt * 16 + lr;
                const float val = acc[mt][nt][j];
                if (ny < 2) {
                    const int n = ny * 128 + nl;
                    const int bi = (m >= LEN_IN) ? 1 : 0;
                    const int pix = m - bi * LEN_IN;
                    valbf[((size_t)((bi << 3) | (n >> 5)) * LEN_IN + pix) * 32 + (n & 31)]
                        = f2bf(val + bias_v[n]);
                } else {
                    const int n = (ny - 2) * 128 + nl;
                    if (n < 256) offsets[(size_t)m * 256 + n] = val + bias_o[n];
                    else logits[(size_t)m * 128 + (n - 256)] = val + bias_a[n - 256];
                }
            }
        }
}

// ---------------------------------------------------------------------------
// Out GEMM: out = inner @ W_out^T + b_out. Same double-buffered skeleton.
// ---------------------------------------------------------------------------
__global__ __launch_bounds__(256) void gemm_out(
    const u16* __restrict__ Ah, const u16* __restrict__ Bh,
    const float* __restrict__ bias0, float* __restrict__ Cf)
{
    __shared__ __align__(16) u16 AS[2][128 * 64];
    __shared__ __align__(16) u16 BS[2][128 * 64];

    const int tid = threadIdx.x;
    const int l = tid & 63, wid = tid >> 6;
    const int wr = wid >> 1, wc = wid & 1;
    const int lr = l & 15;
    const int bm = blockIdx.x * 128, bn = blockIdx.y * 128;

    f32x4 acc[4][4];
#pragma unroll
    for (int i = 0; i < 4; ++i)
#pragma unroll
        for (int j = 0; j < 4; ++j) acc[i][j] = (f32x4)0.f;

    const int rsub = l >> 3;
    const int gs = (l & 7) ^ rsub;

#define STAGE(b, k0)                                                          \
    {                                                                         \
        _Pragma("unroll")                                                     \
        for (int j = 0; j < 4; ++j) {                                         \
            const int ld = wid * 4 + j;                                       \
            const int r  = ld * 8 + rsub;                                     \
            glds16(Ah + (size_t)(bm + r) * 256 + (k0) + gs * 8, &AS[b][ld * 512]); \
            glds16(Bh + (size_t)(bn + r) * 256 + (k0) + gs * 8, &BS[b][ld * 512]); \
        }                                                                     \
    }

    STAGE(0, 0);
    __syncthreads();

#pragma unroll
    for (int kt = 0; kt < 4; ++kt) {
        const int cur = kt & 1;
        if (kt < 3) STAGE(cur ^ 1, (kt + 1) * 64);
#pragma unroll
        for (int kk = 0; kk < 2; ++kk) {
            const int ks = kk * 4 + (l >> 4);
            u16x8 a0[4], b0[4];
#pragma unroll
            for (int t4 = 0; t4 < 4; ++t4) {
                const int ra = wr * 64 + t4 * 16 + lr;
                const int rb = wc * 64 + t4 * 16 + lr;
                a0[t4] = *(const u16x8*)&AS[cur][ra * 64 + ((ks ^ (ra & 7)) * 8)];
                b0[t4] = *(const u16x8*)&BS[cur][rb * 64 + ((ks ^ (rb & 7)) * 8)];
            }
#pragma unroll
            for (int mt = 0; mt < 4; ++mt)
#pragma unroll
                for (int nt = 0; nt < 4; ++nt)
                    MFMA(acc[mt][nt], a0[mt], b0[nt]);
        }
        __syncthreads();
    }
#undef STAGE

    asm volatile("s_nop 7\n\ts_nop 7");

#pragma unroll
    for (int mt = 0; mt < 4; ++mt)
#pragma unroll
        for (int j = 0; j < 4; ++j) {
            const int m = bm + wr * 64 + mt * 16 + (l >> 4) * 4 + j;
            if (m >= MTOT) continue;
#pragma unroll
            for (int nt = 0; nt < 4; ++nt) {
                const int n = bn + wc * 64 + nt * 16 + lr;
                Cf[(size_t)m * 256 + n] = acc[mt][nt][j] + bias0[n];
            }
        }
}

// ---------------------------------------------------------------------------
// Deformable sampling (byte-identical to R6/R7).
// ---------------------------------------------------------------------------
__global__ __launch_bounds__(256) void deform_sample(
    const u16* __restrict__ valbf, const float* __restrict__ offsets,
    const float* __restrict__ logits, const float* __restrict__ refp,
    u16* __restrict__ inner)
{
    const int tid = threadIdx.x;
    const int qi = blockIdx.x * 8 + (tid >> 5);
    if (qi >= MTOT) return;
    const int lq = tid & 31;
    const int g = lq >> 2, d8 = (lq & 3) * 8;
    const int b = (qi >= NQ) ? 1 : 0;

    const float* lg  = logits  + (size_t)qi * 128 + g * 16;
    const float* off = offsets + (size_t)qi * 256 + g * 32;
    const float* ref = refp    + (size_t)qi * 8;
    const u16* vbase = valbf + ((size_t)(b * 8 + g) * LEN_IN) * 32 + d8;

    float w[16];
    float mx = -1e30f;
#pragma unroll
    for (int i = 0; i < 16; ++i) { w[i] = lg[i]; mx = fmaxf(mx, w[i]); }
    float s = 0.f;
#pragma unroll
    for (int i = 0; i < 16; ++i) { w[i] = __expf(w[i] - mx); s += w[i]; }
    const float inv = 1.f / s;

    constexpr int Hs[4] = {92, 46, 23, 12};
    constexpr int Ss[4] = {0, 8464, 10580, 11109};

    float acc[8];
#pragma unroll
    for (int j = 0; j < 8; ++j) acc[j] = 0.f;

#pragma unroll
    for (int l = 0; l < 4; ++l) {
        const int Hn = Hs[l];
        const float Hf = (float)Hn;
        const float rx = ref[l * 2 + 0];
        const float ry = ref[l * 2 + 1];
        const u16* vlev = vbase + (size_t)Ss[l] * 32;

        uint4 cv[16];
        float cw[16];
#pragma unroll
        for (int k = 0; k < 4; ++k) {
            const float ox = off[(l * 4 + k) * 2 + 0];
            const float oy = off[(l * 4 + k) * 2 + 1];
            const float x = (rx + ox / Hf) * Hf - 0.5f;
            const float y = (ry + oy / Hf) * Hf - 0.5f;
            float aw = w[l * 4 + k];
            if (!(y > -1.f && x > -1.f && y < Hf && x < Hf)) aw = 0.f;
            const float h0f = floorf(y), w0f = floorf(x);
            const float lh = y - h0f, lw = x - w0f;
            const float hh = 1.f - lh, hw = 1.f - lw;
            const int h0 = (int)h0f, w0 = (int)w0f;
            const int base = h0 * Hn + w0;
            const bool hv0 = (unsigned)h0 < (unsigned)Hn;
            const bool hv1 = (unsigned)(h0 + 1) < (unsigned)Hn;
            const bool wv0 = (unsigned)w0 < (unsigned)Hn;
            const bool wv1 = (unsigned)(w0 + 1) < (unsigned)Hn;
            const bool v00 = hv0 && wv0, v01 = hv0 && wv1;
            const bool v10 = hv1 && wv0, v11 = hv1 && wv1;
            cw[k * 4 + 0] = v00 ? hh * hw * aw : 0.f;
            cw[k * 4 + 1] = v01 ? hh * lw * aw : 0.f;
            cw[k * 4 + 2] = v10 ? lh * hw * aw : 0.f;
            cw[k * 4 + 3] = v11 ? lh * lw * aw : 0.f;
            cv[k * 4 + 0] = *(const uint4*)(vlev + (size_t)(v00 ? base : 0) * 32);
            cv[k * 4 + 1] = *(const uint4*)(vlev + (size_t)(v01 ? base + 1 : 0) * 32);
            cv[k * 4 + 2] = *(const uint4*)(vlev + (size_t)(v10 ? base + Hn : 0) * 32);
            cv[k * 4 + 3] = *(const uint4*)(vlev + (size_t)(v11 ? base + Hn + 1 : 0) * 32);
        }
#pragma unroll
        for (int i = 0; i < 16; ++i) {
            const float c_ = cw[i];
            const uint4 v = cv[i];
            acc[0] += __uint_as_float(v.x << 16) * c_;
            acc[1] += __uint_as_float(v.x & 0xffff0000u) * c_;
            acc[2] += __uint_as_float(v.y << 16) * c_;
            acc[3] += __uint_as_float(v.y & 0xffff0000u) * c_;
            acc[4] += __uint_as_float(v.z << 16) * c_;
            acc[5] += __uint_as_float(v.z & 0xffff0000u) * c_;
            acc[6] += __uint_as_float(v.w << 16) * c_;
            acc[7] += __uint_as_float(v.w & 0xffff0000u) * c_;
        }
    }

    u16x8 hv;
#pragma unroll
    for (int j = 0; j < 8; ++j) hv[j] = f2bf(acc[j] * inv);
    *(u16x8*)&inner[(size_t)qi * 256 + g * 32 + d8] = hv;
}

// ---------------------------------------------------------------------------
extern "C" void kernel_launch(void* const* d_in, const int* in_sizes, int n_in,
                              void* d_out, int out_size, void* d_ws, size_t ws_size,
                              hipStream_t stream)
{
    const float* query  = (const float*)d_in[0];
    const float* refp   = (const float*)d_in[1];
    const float* inputf = (const float*)d_in[2];
    const float* W_off  = (const float*)d_in[5];
    const float* b_off  = (const float*)d_in[6];
    const float* W_att  = (const float*)d_in[7];
    const float* b_att  = (const float*)d_in[8];
    const float* W_val  = (const float*)d_in[9];
    const float* b_val  = (const float*)d_in[10];
    const float* W_out  = (const float*)d_in[11];
    const float* b_out  = (const float*)d_in[12];
    float* out = (float*)d_out;

    char* ws = (char*)d_ws;
    size_t o = 0;
    float* offsets = (float*)(ws + o); o += (size_t)MTOT * 256 * 4;   // 23.05 MB
    float* logits  = (float*)(ws + o); o += (size_t)MTOT * 128 * 4;   // 11.52 MB
    u16*   valbf   = (u16*)  (ws + o); o += (size_t)MTOT * 256 * 2;   // 11.52 MB
    u16*   ih      = (u16*)  (ws + o); o += (size_t)MPAD * 256 * 2;   // 11.53 MB
    u16*   qh      = (u16*)  (ws + o); o += (size_t)MPAD * 256 * 2;   // 11.53 MB
    u16*   wvh     = (u16*)  (ws + o); o += 256 * 256 * 2;
    u16*   wolh    = (u16*)  (ws + o); o += 384 * 256 * 2;
    u16*   wuh     = (u16*)  (ws + o); o += 256 * 256 * 2;            // ~69.6 MB total
    u16*   inner   = ih;   // disjoint lifetime: ih dead after gemm_s1

    dim3 blk(256);

    hipLaunchKernelGGL(prep, dim3(2816, 2), blk, 0, stream,
                       inputf, query, W_val, W_off, W_att, W_out,
                       ih, qh, wvh, wolh, wuh);

    // fused stage-1: value -> valbf (ny 0..1), [offsets|logits] (ny 2..4)
    hipLaunchKernelGGL(gemm_s1, dim3(176, 5), blk, 0, stream,
                       ih, qh, wvh, wolh, b_val, b_off, b_att,
                       offsets, logits, valbf);

    hipLaunchKernelGGL(deform_sample, dim3((MTOT + 7) / 8), blk, 0, stream,
                       valbf, offsets, logits, refp, inner);

    // out = inner @ W_out + b_out
    hipLaunchKernelGGL(gemm_out, dim3(176, 2), blk, 0, stream,
                       inner, wuh, b_out, out);
}